// Round 1
// baseline (3079.399 us; speedup 1.0000x reference)
//
#include <hip/hip_runtime.h>

#define N_NODES  100000
#define N_EDGES  1600000
#define N_GRAPHS 1024
#define NODE_F   100
#define HID      64
#define GLOB_F   3

// ---------------- degree / norm ----------------
__global__ void k_indeg(const int* __restrict__ dst, int* __restrict__ indeg, int E) {
    int e = blockIdx.x * blockDim.x + threadIdx.x;
    if (e < E) atomicAdd(&indeg[dst[e]], 1);
}

__global__ void k_dinv(const int* __restrict__ indeg, float* __restrict__ dinv, int N) {
    int i = blockIdx.x * blockDim.x + threadIdx.x;
    if (i < N) dinv[i] = 1.0f / sqrtf((float)(1 + indeg[i]));
}

// ---------------- dense MM: Y[N,64] = X[N,K] @ W[K,64] ----------------
// Block = 256 threads, 4 rows/block. W staged fully in LDS.
template <int K>
__global__ void k_mm(const float* __restrict__ X, const float* __restrict__ W,
                     float* __restrict__ Y, int N) {
    __shared__ float Ws[K * HID];
    __shared__ float Xs[4][K];
    int tid = threadIdx.x;
    for (int i = tid; i < K * HID; i += 256) Ws[i] = W[i];
    int row0 = blockIdx.x * 4;
    for (int i = tid; i < 4 * K; i += 256) {
        int r = row0 + i / K;
        Xs[i / K][i % K] = (r < N) ? X[(long long)r * K + (i % K)] : 0.0f;
    }
    __syncthreads();
    int ty = tid >> 6;          // row within block (wave-uniform)
    int c  = tid & 63;          // output column
    int r  = row0 + ty;
    if (r < N) {
        float acc = 0.0f;
#pragma unroll
        for (int k = 0; k < K; ++k) acc += Xs[ty][k] * Ws[k * HID + c];
        Y[(long long)r * HID + c] = acc;
    }
}

// ---------------- edge scatter: acc[dst] += H[src] * dinv[src]*dinv[dst] ----------------
// 16 lanes per edge, float4 per lane.
__global__ void k_scatter(const float* __restrict__ H, const int* __restrict__ src,
                          const int* __restrict__ dst, const float* __restrict__ dinv,
                          float* __restrict__ acc, int E) {
    int gid = blockIdx.x * blockDim.x + threadIdx.x;
    int e = gid >> 4;
    if (e >= E) return;
    int j = (gid & 15) * 4;
    int s = src[e], d = dst[e];
    float nrm = dinv[s] * dinv[d];
    const float4 hv = *reinterpret_cast<const float4*>(H + (long long)s * HID + j);
    float* a = acc + (long long)d * HID + j;
    unsafeAtomicAdd(a + 0, hv.x * nrm);
    unsafeAtomicAdd(a + 1, hv.y * nrm);
    unsafeAtomicAdd(a + 2, hv.z * nrm);
    unsafeAtomicAdd(a + 3, hv.w * nrm);
}

// ---------------- conv1 epilogue: acc = relu(acc + Hmm*dinv^2 + b) ----------------
__global__ void k_epi1(float* __restrict__ acc, const float* __restrict__ Hmm,
                       const float* __restrict__ dinv, const float* __restrict__ b, int N) {
    int idx = blockIdx.x * blockDim.x + threadIdx.x;
    if (idx >= N * HID) return;
    int i = idx >> 6, f = idx & 63;
    float dv = dinv[i];
    float v = acc[idx] + Hmm[idx] * dv * dv + b[f];
    acc[idx] = fmaxf(v, 0.0f);
}

// ---------------- conv2 epilogue fused with global mean pool accumulation ----------------
__global__ void k_epi2_pool(const float* __restrict__ acc, const float* __restrict__ Hmm,
                            const float* __restrict__ dinv, const float* __restrict__ b,
                            const int* __restrict__ batch,
                            float* __restrict__ pooled, float* __restrict__ cnt, int N) {
    int idx = blockIdx.x * blockDim.x + threadIdx.x;
    if (idx >= N * HID) return;
    int i = idx >> 6, f = idx & 63;
    float dv = dinv[i];
    float v = acc[idx] + Hmm[idx] * dv * dv + b[f];
    int g = batch[i];
    unsafeAtomicAdd(&pooled[g * HID + f], v);
    if (f == 0) unsafeAtomicAdd(&cnt[g], 1.0f);
}

// ---------------- MLP head: one wave (64 threads) per graph ----------------
__global__ void k_head(const float* __restrict__ pooled, const float* __restrict__ cnt,
                       const float* __restrict__ gf,
                       const float* __restrict__ gW1, const float* __restrict__ gb1,
                       const float* __restrict__ gW2, const float* __restrict__ gb2,
                       const float* __restrict__ cW1, const float* __restrict__ cb1,
                       const float* __restrict__ cW2, const float* __restrict__ cb2,
                       float* __restrict__ out) {
    int g = blockIdx.x;
    int f = threadIdx.x;   // 0..63
    __shared__ float gh[HID];
    __shared__ float comb[2 * HID];

    // global MLP layer 1: relu(gf @ gW1 + gb1)
    float a = gb1[f];
#pragma unroll
    for (int k = 0; k < GLOB_F; ++k) a += gf[g * GLOB_F + k] * gW1[k * HID + f];
    gh[f] = fmaxf(a, 0.0f);
    __syncthreads();

    // layer 2: gh @ gW2 + gb2
    float a2 = gb2[f];
#pragma unroll 8
    for (int k = 0; k < HID; ++k) a2 += gh[k] * gW2[k * HID + f];

    float c = cnt[g];
    comb[f] = pooled[g * HID + f] / fmaxf(c, 1.0f);
    comb[HID + f] = a2;
    __syncthreads();

    // head layer 1: relu(comb @ cW1 + cb1)
    float a3 = cb1[f];
#pragma unroll 8
    for (int k = 0; k < 2 * HID; ++k) a3 += comb[k] * cW1[k * HID + f];
    a3 = fmaxf(a3, 0.0f);

    // head layer 2: dot with cW2[:,0], wave-reduce 64 lanes
    float prod = a3 * cW2[f];
#pragma unroll
    for (int off = 32; off > 0; off >>= 1) prod += __shfl_down(prod, off);
    if (f == 0) out[g] = prod + cb2[0];
}

extern "C" void kernel_launch(void* const* d_in, const int* in_sizes, int n_in,
                              void* d_out, int out_size, void* d_ws, size_t ws_size,
                              hipStream_t stream) {
    const float* x     = (const float*)d_in[0];
    const int*   ei    = (const int*)d_in[1];
    const int*   batch = (const int*)d_in[2];
    const float* gf    = (const float*)d_in[3];
    const float* W1    = (const float*)d_in[4];
    const float* b1    = (const float*)d_in[5];
    const float* W2    = (const float*)d_in[6];
    const float* b2    = (const float*)d_in[7];
    const float* gW1   = (const float*)d_in[8];
    const float* gb1   = (const float*)d_in[9];
    const float* gW2   = (const float*)d_in[10];
    const float* gb2   = (const float*)d_in[11];
    const float* cW1   = (const float*)d_in[12];
    const float* cb1   = (const float*)d_in[13];
    const float* cW2   = (const float*)d_in[14];
    const float* cb2   = (const float*)d_in[15];
    float* out = (float*)d_out;

    const int* src = ei;
    const int* dst = ei + N_EDGES;

    // workspace layout
    char* w = (char*)d_ws;
    float* bufA   = (float*)w;  w += (size_t)N_NODES * HID * sizeof(float);   // 25.6 MB
    float* bufB   = (float*)w;  w += (size_t)N_NODES * HID * sizeof(float);   // 25.6 MB
    int*   indeg  = (int*)w;    w += (size_t)N_NODES * sizeof(int);
    float* dinv   = (float*)w;  w += (size_t)N_NODES * sizeof(float);
    float* pooled = (float*)w;  w += (size_t)N_GRAPHS * HID * sizeof(float);
    float* cnt    = (float*)w;  w += (size_t)N_GRAPHS * sizeof(float);

    const int BT = 256;

    // degree + norm
    hipMemsetAsync(indeg, 0, (size_t)N_NODES * sizeof(int), stream);
    k_indeg<<<(N_EDGES + BT - 1) / BT, BT, 0, stream>>>(dst, indeg, N_EDGES);
    k_dinv<<<(N_NODES + BT - 1) / BT, BT, 0, stream>>>(indeg, dinv, N_NODES);

    // conv1
    k_mm<NODE_F><<<(N_NODES + 3) / 4, BT, 0, stream>>>(x, W1, bufA, N_NODES);
    hipMemsetAsync(bufB, 0, (size_t)N_NODES * HID * sizeof(float), stream);
    k_scatter<<<((size_t)N_EDGES * 16 + BT - 1) / BT, BT, 0, stream>>>(bufA, src, dst, dinv, bufB, N_EDGES);
    k_epi1<<<(N_NODES * HID + BT - 1) / BT, BT, 0, stream>>>(bufB, bufA, dinv, b1, N_NODES);

    // conv2
    k_mm<HID><<<(N_NODES + 3) / 4, BT, 0, stream>>>(bufB, W2, bufA, N_NODES);
    hipMemsetAsync(bufB, 0, (size_t)N_NODES * HID * sizeof(float), stream);
    k_scatter<<<((size_t)N_EDGES * 16 + BT - 1) / BT, BT, 0, stream>>>(bufA, src, dst, dinv, bufB, N_EDGES);

    // conv2 epilogue + mean-pool accumulation
    hipMemsetAsync(pooled, 0, (size_t)(N_GRAPHS * HID + N_GRAPHS) * sizeof(float), stream);
    k_epi2_pool<<<(N_NODES * HID + BT - 1) / BT, BT, 0, stream>>>(bufB, bufA, dinv, b2, batch,
                                                                  pooled, cnt, N_NODES);

    // MLP head
    k_head<<<N_GRAPHS, HID, 0, stream>>>(pooled, cnt, gf, gW1, gb1, gW2, gb2,
                                         cW1, cb1, cW2, cb2, out);
}

// Round 2
// 837.034 us; speedup vs baseline: 3.6789x; 3.6789x over previous
//
#include <hip/hip_runtime.h>

#define N_NODES  100000
#define N_EDGES  1600000
#define N_GRAPHS 1024
#define NODE_F   100
#define HID      64
#define GLOB_F   3

// ---------------- degree ----------------
__global__ void k_indeg(const int* __restrict__ dst, int* __restrict__ indeg, int E) {
    int e = blockIdx.x * blockDim.x + threadIdx.x;
    if (e < E) atomicAdd(&indeg[dst[e]], 1);
}

__global__ void k_dinv(const int* __restrict__ indeg, float* __restrict__ dinv, int N) {
    int i = blockIdx.x * blockDim.x + threadIdx.x;
    if (i < N) dinv[i] = 1.0f / sqrtf((float)(1 + indeg[i]));
}

// ---------------- exclusive scan over indeg -> rowoff, cursor (single block) ----------------
__global__ void k_scan(const int* __restrict__ indeg, int* __restrict__ rowoff,
                       int* __restrict__ cursor, int N) {
    __shared__ int part[1024];
    int t = threadIdx.x;
    const int chunk = (N + 1023) / 1024;
    int lo = t * chunk;
    int hi = lo + chunk; if (hi > N) hi = N;
    int s = 0;
    for (int i = lo; i < hi; ++i) s += indeg[i];
    part[t] = s;
    __syncthreads();
    // inclusive Hillis-Steele scan on part[]
    for (int off = 1; off < 1024; off <<= 1) {
        int o = (t >= off) ? part[t - off] : 0;
        __syncthreads();
        part[t] += o;
        __syncthreads();
    }
    int run = part[t] - s;  // exclusive prefix for this chunk
    for (int i = lo; i < hi; ++i) {
        rowoff[i] = run;
        cursor[i] = run;
        run += indeg[i];
    }
    if (t == 1023) rowoff[N] = run;
}

// ---------------- bucket edges by dst -> csrc ----------------
__global__ void k_bucket(const int* __restrict__ src, const int* __restrict__ dst,
                         int* __restrict__ cursor, int* __restrict__ csrc, int E) {
    int e = blockIdx.x * blockDim.x + threadIdx.x;
    if (e < E) {
        int pos = atomicAdd(&cursor[dst[e]], 1);
        csrc[pos] = src[e];
    }
}

// ---------------- dense MM with dinv row-scale: Y[r,c] = (X[r,:]@W[:,c]) * dinv[r] ----------------
template <int K>
__global__ void k_mm(const float* __restrict__ X, const float* __restrict__ W,
                     const float* __restrict__ dinv, float* __restrict__ Y, int N) {
    __shared__ float Ws[K * HID];
    __shared__ float Xs[4][K];
    int tid = threadIdx.x;
    for (int i = tid; i < K * HID; i += 256) Ws[i] = W[i];
    int row0 = blockIdx.x * 4;
    for (int i = tid; i < 4 * K; i += 256) {
        int r = row0 + i / K;
        Xs[i / K][i % K] = (r < N) ? X[(long long)r * K + (i % K)] : 0.0f;
    }
    __syncthreads();
    int ty = tid >> 6;
    int c  = tid & 63;
    int r  = row0 + ty;
    if (r < N) {
        float acc = 0.0f;
#pragma unroll
        for (int k = 0; k < K; ++k) acc += Xs[ty][k] * Ws[k * HID + c];
        Y[(long long)r * HID + c] = acc * dinv[r];
    }
}

// ---------------- per-dst gather: out[d] = dinv[d]*(sum Hs[src] + Hs[d]) + b ----------------
// 64 lanes per dst node, 4 nodes per 256-thread block.
template <int RELU, int POOL>
__global__ void k_gather(const float* __restrict__ Hs, const int* __restrict__ rowoff,
                         const int* __restrict__ csrc, const float* __restrict__ dinv,
                         const float* __restrict__ b, float* __restrict__ outbuf,
                         const int* __restrict__ batch, float* __restrict__ pooled,
                         float* __restrict__ cnt, int N) {
    int tid = threadIdx.x;
    int d = blockIdx.x * 4 + (tid >> 6);
    if (d >= N) return;
    int f = tid & 63;
    int lo = rowoff[d], hi = rowoff[d + 1];
    float acc = Hs[(long long)d * HID + f];  // self-loop term
    int e = lo;
    for (; e + 4 <= hi; e += 4) {
        int s0 = csrc[e], s1 = csrc[e + 1], s2 = csrc[e + 2], s3 = csrc[e + 3];
        float a0 = Hs[(long long)s0 * HID + f];
        float a1 = Hs[(long long)s1 * HID + f];
        float a2 = Hs[(long long)s2 * HID + f];
        float a3 = Hs[(long long)s3 * HID + f];
        acc += a0; acc += a1; acc += a2; acc += a3;
    }
    for (; e < hi; ++e) acc += Hs[(long long)csrc[e] * HID + f];
    float v = acc * dinv[d] + b[f];
    if (RELU) v = fmaxf(v, 0.0f);
    if (POOL) {
        int g = batch[d];
        unsafeAtomicAdd(&pooled[g * HID + f], v);
        if (f == 0) unsafeAtomicAdd(&cnt[g], 1.0f);
    } else {
        outbuf[(long long)d * HID + f] = v;
    }
}

// ---------------- MLP head: one wave (64 threads) per graph ----------------
__global__ void k_head(const float* __restrict__ pooled, const float* __restrict__ cnt,
                       const float* __restrict__ gf,
                       const float* __restrict__ gW1, const float* __restrict__ gb1,
                       const float* __restrict__ gW2, const float* __restrict__ gb2,
                       const float* __restrict__ cW1, const float* __restrict__ cb1,
                       const float* __restrict__ cW2, const float* __restrict__ cb2,
                       float* __restrict__ out) {
    int g = blockIdx.x;
    int f = threadIdx.x;   // 0..63
    __shared__ float gh[HID];
    __shared__ float comb[2 * HID];

    float a = gb1[f];
#pragma unroll
    for (int k = 0; k < GLOB_F; ++k) a += gf[g * GLOB_F + k] * gW1[k * HID + f];
    gh[f] = fmaxf(a, 0.0f);
    __syncthreads();

    float a2 = gb2[f];
#pragma unroll 8
    for (int k = 0; k < HID; ++k) a2 += gh[k] * gW2[k * HID + f];

    float c = cnt[g];
    comb[f] = pooled[g * HID + f] / fmaxf(c, 1.0f);
    comb[HID + f] = a2;
    __syncthreads();

    float a3 = cb1[f];
#pragma unroll 8
    for (int k = 0; k < 2 * HID; ++k) a3 += comb[k] * cW1[k * HID + f];
    a3 = fmaxf(a3, 0.0f);

    float prod = a3 * cW2[f];
#pragma unroll
    for (int off = 32; off > 0; off >>= 1) prod += __shfl_down(prod, off);
    if (f == 0) out[g] = prod + cb2[0];
}

extern "C" void kernel_launch(void* const* d_in, const int* in_sizes, int n_in,
                              void* d_out, int out_size, void* d_ws, size_t ws_size,
                              hipStream_t stream) {
    const float* x     = (const float*)d_in[0];
    const int*   ei    = (const int*)d_in[1];
    const int*   batch = (const int*)d_in[2];
    const float* gf    = (const float*)d_in[3];
    const float* W1    = (const float*)d_in[4];
    const float* b1    = (const float*)d_in[5];
    const float* W2    = (const float*)d_in[6];
    const float* b2    = (const float*)d_in[7];
    const float* gW1   = (const float*)d_in[8];
    const float* gb1   = (const float*)d_in[9];
    const float* gW2   = (const float*)d_in[10];
    const float* gb2   = (const float*)d_in[11];
    const float* cW1   = (const float*)d_in[12];
    const float* cb1   = (const float*)d_in[13];
    const float* cW2   = (const float*)d_in[14];
    const float* cb2   = (const float*)d_in[15];
    float* out = (float*)d_out;

    const int* src = ei;
    const int* dst = ei + N_EDGES;

    // workspace layout (~59.5 MB)
    char* w = (char*)d_ws;
    float* bufA   = (float*)w;  w += (size_t)N_NODES * HID * sizeof(float);   // Hs (scaled MM out)
    float* bufB   = (float*)w;  w += (size_t)N_NODES * HID * sizeof(float);   // conv1 out
    int*   indeg  = (int*)w;    w += (size_t)N_NODES * sizeof(int);
    float* dinv   = (float*)w;  w += (size_t)N_NODES * sizeof(float);
    int*   rowoff = (int*)w;    w += (size_t)(N_NODES + 1) * sizeof(int);
    int*   cursor = (int*)w;    w += (size_t)N_NODES * sizeof(int);
    int*   csrc   = (int*)w;    w += (size_t)N_EDGES * sizeof(int);
    float* pooled = (float*)w;  w += (size_t)N_GRAPHS * HID * sizeof(float);
    float* cnt    = (float*)w;  w += (size_t)N_GRAPHS * sizeof(float);

    const int BT = 256;

    // ---- CSR build ----
    hipMemsetAsync(indeg, 0, (size_t)N_NODES * sizeof(int), stream);
    k_indeg<<<(N_EDGES + BT - 1) / BT, BT, 0, stream>>>(dst, indeg, N_EDGES);
    k_dinv<<<(N_NODES + BT - 1) / BT, BT, 0, stream>>>(indeg, dinv, N_NODES);
    k_scan<<<1, 1024, 0, stream>>>(indeg, rowoff, cursor, N_NODES);
    k_bucket<<<(N_EDGES + BT - 1) / BT, BT, 0, stream>>>(src, dst, cursor, csrc, N_EDGES);

    // ---- conv1: Hs = (x@W1)*dinv ; bufB = relu(dinv*(gather+self) + b1) ----
    k_mm<NODE_F><<<(N_NODES + 3) / 4, BT, 0, stream>>>(x, W1, dinv, bufA, N_NODES);
    k_gather<1, 0><<<(N_NODES + 3) / 4, BT, 0, stream>>>(bufA, rowoff, csrc, dinv, b1,
                                                         bufB, nullptr, nullptr, nullptr, N_NODES);

    // ---- conv2 fused with mean-pool accumulation ----
    k_mm<HID><<<(N_NODES + 3) / 4, BT, 0, stream>>>(bufB, W2, dinv, bufA, N_NODES);
    hipMemsetAsync(pooled, 0, (size_t)(N_GRAPHS * HID + N_GRAPHS) * sizeof(float), stream);
    k_gather<0, 1><<<(N_NODES + 3) / 4, BT, 0, stream>>>(bufA, rowoff, csrc, dinv, b2,
                                                         nullptr, batch, pooled, cnt, N_NODES);

    // ---- MLP head ----
    k_head<<<N_GRAPHS, HID, 0, stream>>>(pooled, cnt, gf, gW1, gb1, gW2, gb2,
                                         cW1, cb1, cW2, cb2, out);
}

// Round 3
// 606.391 us; speedup vs baseline: 5.0782x; 1.3804x over previous
//
#include <hip/hip_runtime.h>

#define N_NODES  100000
#define N_EDGES  1600000
#define N_GRAPHS 1024
#define NODE_F   100
#define HID      64
#define GLOB_F   3

#define SCAN_CHUNK 1024                       // elements per block (256 thr * 4)
#define SCAN_NB    ((N_NODES + SCAN_CHUNK - 1) / SCAN_CHUNK)   // 98

// ---------------- degree ----------------
__global__ void k_indeg(const int* __restrict__ dst, int* __restrict__ indeg, int E) {
    int e = blockIdx.x * blockDim.x + threadIdx.x;
    if (e < E) atomicAdd(&indeg[dst[e]], 1);
}

// ---------------- multi-block exclusive scan ----------------
// phase 1: per-block sums
__global__ void k_scan1(const int* __restrict__ indeg, int* __restrict__ blocksum, int N) {
    __shared__ int red[256];
    int t = threadIdx.x;
    int base = blockIdx.x * SCAN_CHUNK + t * 4;
    int s = 0;
#pragma unroll
    for (int j = 0; j < 4; ++j) { int i = base + j; if (i < N) s += indeg[i]; }
    red[t] = s;
    __syncthreads();
    for (int off = 128; off > 0; off >>= 1) {
        if (t < off) red[t] += red[t + off];
        __syncthreads();
    }
    if (t == 0) blocksum[blockIdx.x] = red[0];
}

// phase 2: exclusive scan of block sums (NB <= 128), single tiny block
__global__ void k_scan2(int* __restrict__ blocksum, int NB) {
    __shared__ int sh[128];
    int t = threadIdx.x;
    int v = (t < NB) ? blocksum[t] : 0;
    sh[t] = v;
    __syncthreads();
    for (int off = 1; off < 128; off <<= 1) {
        int o = (t >= off) ? sh[t - off] : 0;
        __syncthreads();
        sh[t] += o;
        __syncthreads();
    }
    if (t < NB) blocksum[t] = sh[t] - v;   // exclusive
}

// phase 3: block-local exclusive scan + global offset; writes rowoff, cursor, dinv
__global__ void k_scan3(const int* __restrict__ indeg, const int* __restrict__ blocksum,
                        int* __restrict__ rowoff, int* __restrict__ cursor,
                        float* __restrict__ dinv, int N) {
    __shared__ int sh[256];
    int t = threadIdx.x;
    int base = blockIdx.x * SCAN_CHUNK + t * 4;
    int loc[4];
    int s = 0;
#pragma unroll
    for (int j = 0; j < 4; ++j) {
        int i = base + j;
        loc[j] = (i < N) ? indeg[i] : 0;
        s += loc[j];
    }
    sh[t] = s;
    __syncthreads();
    for (int off = 1; off < 256; off <<= 1) {
        int o = (t >= off) ? sh[t - off] : 0;
        __syncthreads();
        sh[t] += o;
        __syncthreads();
    }
    int run = blocksum[blockIdx.x] + sh[t] - s;   // exclusive prefix for this thread
#pragma unroll
    for (int j = 0; j < 4; ++j) {
        int i = base + j;
        if (i < N) {
            rowoff[i] = run;
            cursor[i] = run;
            dinv[i] = 1.0f / sqrtf((float)(1 + loc[j]));
            run += loc[j];
            if (i == N - 1) rowoff[N] = run;
        }
    }
}

// ---------------- bucket edges by dst -> csrc ----------------
__global__ void k_bucket(const int* __restrict__ src, const int* __restrict__ dst,
                         int* __restrict__ cursor, int* __restrict__ csrc, int E) {
    int e = blockIdx.x * blockDim.x + threadIdx.x;
    if (e < E) {
        int pos = atomicAdd(&cursor[dst[e]], 1);
        csrc[pos] = src[e];
    }
}

// ---------------- dense MM with dinv row-scale: Y[r,c] = (X[r,:]@W[:,c]) * dinv[r] ----------------
template <int K>
__global__ void k_mm(const float* __restrict__ X, const float* __restrict__ W,
                     const float* __restrict__ dinv, float* __restrict__ Y, int N) {
    __shared__ float Ws[K * HID];
    __shared__ float Xs[4][K];
    int tid = threadIdx.x;
    for (int i = tid; i < K * HID; i += 256) Ws[i] = W[i];
    int row0 = blockIdx.x * 4;
    for (int i = tid; i < 4 * K; i += 256) {
        int r = row0 + i / K;
        Xs[i / K][i % K] = (r < N) ? X[(long long)r * K + (i % K)] : 0.0f;
    }
    __syncthreads();
    int ty = tid >> 6;
    int c  = tid & 63;
    int r  = row0 + ty;
    if (r < N) {
        float acc = 0.0f;
#pragma unroll
        for (int k = 0; k < K; ++k) acc += Xs[ty][k] * Ws[k * HID + c];
        Y[(long long)r * HID + c] = acc * dinv[r];
    }
}

// ---------------- per-dst gather: out[d] = dinv[d]*(sum Hs[src] + Hs[d]) + b ----------------
template <int RELU, int POOL>
__global__ void k_gather(const float* __restrict__ Hs, const int* __restrict__ rowoff,
                         const int* __restrict__ csrc, const float* __restrict__ dinv,
                         const float* __restrict__ b, float* __restrict__ outbuf,
                         const int* __restrict__ batch, float* __restrict__ pooled,
                         float* __restrict__ cnt, int N) {
    int tid = threadIdx.x;
    int d = blockIdx.x * 4 + (tid >> 6);
    if (d >= N) return;
    int f = tid & 63;
    int lo = rowoff[d], hi = rowoff[d + 1];
    float acc = Hs[(long long)d * HID + f];  // self-loop term
    int e = lo;
    for (; e + 4 <= hi; e += 4) {
        int s0 = csrc[e], s1 = csrc[e + 1], s2 = csrc[e + 2], s3 = csrc[e + 3];
        float a0 = Hs[(long long)s0 * HID + f];
        float a1 = Hs[(long long)s1 * HID + f];
        float a2 = Hs[(long long)s2 * HID + f];
        float a3 = Hs[(long long)s3 * HID + f];
        acc += a0; acc += a1; acc += a2; acc += a3;
    }
    for (; e < hi; ++e) acc += Hs[(long long)csrc[e] * HID + f];
    float v = acc * dinv[d] + b[f];
    if (RELU) v = fmaxf(v, 0.0f);
    if (POOL) {
        int g = batch[d];
        unsafeAtomicAdd(&pooled[g * HID + f], v);
        if (f == 0) unsafeAtomicAdd(&cnt[g], 1.0f);
    } else {
        outbuf[(long long)d * HID + f] = v;
    }
}

// ---------------- MLP head: one wave (64 threads) per graph ----------------
__global__ void k_head(const float* __restrict__ pooled, const float* __restrict__ cnt,
                       const float* __restrict__ gf,
                       const float* __restrict__ gW1, const float* __restrict__ gb1,
                       const float* __restrict__ gW2, const float* __restrict__ gb2,
                       const float* __restrict__ cW1, const float* __restrict__ cb1,
                       const float* __restrict__ cW2, const float* __restrict__ cb2,
                       float* __restrict__ out) {
    int g = blockIdx.x;
    int f = threadIdx.x;   // 0..63
    __shared__ float gh[HID];
    __shared__ float comb[2 * HID];

    float a = gb1[f];
#pragma unroll
    for (int k = 0; k < GLOB_F; ++k) a += gf[g * GLOB_F + k] * gW1[k * HID + f];
    gh[f] = fmaxf(a, 0.0f);
    __syncthreads();

    float a2 = gb2[f];
#pragma unroll 8
    for (int k = 0; k < HID; ++k) a2 += gh[k] * gW2[k * HID + f];

    float c = cnt[g];
    comb[f] = pooled[g * HID + f] / fmaxf(c, 1.0f);
    comb[HID + f] = a2;
    __syncthreads();

    float a3 = cb1[f];
#pragma unroll 8
    for (int k = 0; k < 2 * HID; ++k) a3 += comb[k] * cW1[k * HID + f];
    a3 = fmaxf(a3, 0.0f);

    float prod = a3 * cW2[f];
#pragma unroll
    for (int off = 32; off > 0; off >>= 1) prod += __shfl_down(prod, off);
    if (f == 0) out[g] = prod + cb2[0];
}

extern "C" void kernel_launch(void* const* d_in, const int* in_sizes, int n_in,
                              void* d_out, int out_size, void* d_ws, size_t ws_size,
                              hipStream_t stream) {
    const float* x     = (const float*)d_in[0];
    const int*   ei    = (const int*)d_in[1];
    const int*   batch = (const int*)d_in[2];
    const float* gf    = (const float*)d_in[3];
    const float* W1    = (const float*)d_in[4];
    const float* b1    = (const float*)d_in[5];
    const float* W2    = (const float*)d_in[6];
    const float* b2    = (const float*)d_in[7];
    const float* gW1   = (const float*)d_in[8];
    const float* gb1   = (const float*)d_in[9];
    const float* gW2   = (const float*)d_in[10];
    const float* gb2   = (const float*)d_in[11];
    const float* cW1   = (const float*)d_in[12];
    const float* cb1   = (const float*)d_in[13];
    const float* cW2   = (const float*)d_in[14];
    const float* cb2   = (const float*)d_in[15];
    float* out = (float*)d_out;

    const int* src = ei;
    const int* dst = ei + N_EDGES;

    // workspace layout (~59.5 MB)
    char* w = (char*)d_ws;
    float* bufA     = (float*)w;  w += (size_t)N_NODES * HID * sizeof(float);
    float* bufB     = (float*)w;  w += (size_t)N_NODES * HID * sizeof(float);
    int*   indeg    = (int*)w;    w += (size_t)N_NODES * sizeof(int);
    float* dinv     = (float*)w;  w += (size_t)N_NODES * sizeof(float);
    int*   rowoff   = (int*)w;    w += (size_t)(N_NODES + 1) * sizeof(int);
    int*   cursor   = (int*)w;    w += (size_t)N_NODES * sizeof(int);
    int*   csrc     = (int*)w;    w += (size_t)N_EDGES * sizeof(int);
    int*   blocksum = (int*)w;    w += (size_t)SCAN_NB * sizeof(int);
    float* pooled   = (float*)w;  w += (size_t)N_GRAPHS * HID * sizeof(float);
    float* cnt      = (float*)w;  w += (size_t)N_GRAPHS * sizeof(float);

    const int BT = 256;

    // ---- CSR build ----
    hipMemsetAsync(indeg, 0, (size_t)N_NODES * sizeof(int), stream);
    k_indeg<<<(N_EDGES + BT - 1) / BT, BT, 0, stream>>>(dst, indeg, N_EDGES);
    k_scan1<<<SCAN_NB, BT, 0, stream>>>(indeg, blocksum, N_NODES);
    k_scan2<<<1, 128, 0, stream>>>(blocksum, SCAN_NB);
    k_scan3<<<SCAN_NB, BT, 0, stream>>>(indeg, blocksum, rowoff, cursor, dinv, N_NODES);
    k_bucket<<<(N_EDGES + BT - 1) / BT, BT, 0, stream>>>(src, dst, cursor, csrc, N_EDGES);

    // ---- conv1: Hs = (x@W1)*dinv ; bufB = relu(dinv*(gather+self) + b1) ----
    k_mm<NODE_F><<<(N_NODES + 3) / 4, BT, 0, stream>>>(x, W1, dinv, bufA, N_NODES);
    k_gather<1, 0><<<(N_NODES + 3) / 4, BT, 0, stream>>>(bufA, rowoff, csrc, dinv, b1,
                                                         bufB, nullptr, nullptr, nullptr, N_NODES);

    // ---- conv2 fused with mean-pool accumulation ----
    k_mm<HID><<<(N_NODES + 3) / 4, BT, 0, stream>>>(bufB, W2, dinv, bufA, N_NODES);
    hipMemsetAsync(pooled, 0, (size_t)(N_GRAPHS * HID + N_GRAPHS) * sizeof(float), stream);
    k_gather<0, 1><<<(N_NODES + 3) / 4, BT, 0, stream>>>(bufA, rowoff, csrc, dinv, b2,
                                                         nullptr, batch, pooled, cnt, N_NODES);

    // ---- MLP head ----
    k_head<<<N_GRAPHS, HID, 0, stream>>>(pooled, cnt, gf, gW1, gb1, gW2, gb2,
                                         cW1, cb1, cW2, cb2, out);
}